// Round 9
// baseline (257.031 us; speedup 1.0000x reference)
//
#include <hip/hip_runtime.h>
#include <hip/hip_bf16.h>

// Problem constants (B,N,D,H from reference)
#define Bc 64
#define Nc 512
#define Dc 1024
#define Hc 2048
#define Mc (Bc * Nc)          // 32768 rows

// GEMM tiling: 256x256 tile, BK=64, 8 waves (2M x 4N).
// A staged via LDS (4x reuse, dbuf 2x32KB); B loaded global->VGPR direct
// (2x reuse, L2-resident W1), double-buffered in registers.
#define BM 256
#define BH 256
#define BK 64
#define KTILES (Dc / BK)      // 16
#define MTILES (Mc / BM)      // 128
#define HTILES (Hc / BH)      // 8
#define NSLICE (HTILES * 4)   // 32 score slices (ht x wave-column)

typedef __attribute__((ext_vector_type(8))) short bf16x8;
typedef __attribute__((ext_vector_type(4))) float f32x4;

__device__ __forceinline__ unsigned short f2bf(float f) {
    unsigned u = __float_as_uint(f);
    u += 0x7FFFu + ((u >> 16) & 1u);   // RNE
    return (unsigned short)(u >> 16);
}

__device__ __forceinline__ void stage16(const void* g, void* l) {
    __builtin_amdgcn_global_load_lds(
        (const __attribute__((address_space(1))) unsigned int*)g,
        (__attribute__((address_space(3))) unsigned int*)l,
        16, 0, 0);
}

// ------- Kernel A: fused {cast x + energy} | {cast W1} (one launch) ---------
__global__ void __launch_bounds__(256) cast_fused(
    const float* __restrict__ x, const float* __restrict__ w1,
    unsigned short* __restrict__ xb, unsigned short* __restrict__ w1b,
    float* __restrict__ energy)
{
    const int tid = threadIdx.x;
    if (blockIdx.x < Mc) {
        const int row = blockIdx.x;            // 0..Mc-1
        const float4 v = ((const float4*)(x + (size_t)row * Dc))[tid];
        ushort4 o;
        o.x = f2bf(v.x); o.y = f2bf(v.y); o.z = f2bf(v.z); o.w = f2bf(v.w);
        ((ushort4*)(xb + (size_t)row * Dc))[tid] = o;

        float s = v.x * v.x + v.y * v.y + v.z * v.z + v.w * v.w;
        #pragma unroll
        for (int m = 1; m < 64; m <<= 1) s += __shfl_xor(s, m);
        __shared__ float ws[4];
        if ((tid & 63) == 0) ws[tid >> 6] = s;
        __syncthreads();
        if (tid == 0) {
            float t = ws[0] + ws[1] + ws[2] + ws[3];
            energy[row] = 1.0f / (1.0f + expf(-t));
        }
    } else {
        const size_t i = (size_t)(blockIdx.x - Mc) * 256 + tid; // x4 elems
        const float4 v = ((const float4*)w1)[i];
        ushort4 o;
        o.x = f2bf(v.x); o.y = f2bf(v.y); o.z = f2bf(v.z); o.w = f2bf(v.w);
        ((ushort4*)w1b)[i] = o;
    }
}

// ---------------- Kernel C: fused bf16 GEMM + relu + W2-reduce --------------
// 256x256 tile, 8 waves. A: LDS dbuf + global_load_lds prefetch-1.
// B: direct global->VGPR fragment gathers (16 rows x 128B per instr, L2-hot),
// register double-buffer pBe/pBo loaded one full tile ahead.
// score_part[(ht*4 + wc)*Mc + row] = sum over slice's 64 h of
//     relu(x.W1[h] + b1[h]) * W2[h]
__global__ void __launch_bounds__(512, 2) fused_gemm_score(
    const unsigned short* __restrict__ xb,    // [Mc][Dc] bf16 bits
    const unsigned short* __restrict__ w1b,   // [Hc][Dc] bf16 bits
    const float* __restrict__ b1,             // [Hc]
    const float* __restrict__ w2,             // [Hc]
    float* __restrict__ score_part)           // [NSLICE][Mc]
{
    // dynamic LDS: [2 buf][256 x 64] bf16 A panels = 64 KB
    extern __shared__ __attribute__((aligned(16))) char lds[];

    const int tid  = threadIdx.x;
    const int lane = tid & 63;
    const int wid  = tid >> 6;                // 0..7
    const int wr   = wid >> 2;                // 0..1  (m half: 128 rows)
    const int wc   = wid & 3;                 // 0..3  (h quarter: 64 cols)
    const int l15  = lane & 15;
    const int l4   = lane >> 4;               // 0..3

    // bijective XCD swizzle (1024 % 8 == 0): ht fastest within an XCD so the
    // 8 blocks sharing one x-tile run adjacently; W1 (4MB) stays L2-resident.
    const int b  = blockIdx.x;
    const int wg = (b & 7) * (MTILES * HTILES / 8) + (b >> 3);
    const int mt = wg >> 3;                   // 0..127
    const int ht = wg & 7;                    // 0..7
    const int m0 = mt * BM;
    const int h0 = ht * BH;

    // epilogue coefficients prefetch
    float b1v[4], w2v[4];
    #pragma unroll
    for (int n = 0; n < 4; ++n) {
        const int h = h0 + wc * 64 + n * 16 + l15;
        b1v[n] = b1[h];
        w2v[n] = w2[h];
    }

    // A staging geometry (rule #21: linear LDS dest + pre-swizzled src col)
    const int srow    = tid >> 3;             // 0..63
    const int scol_sw = ((((tid & 7) * 16) ^ ((srow & 7) << 4)) >> 1); // elems

#define LDSA(bf) (lds + (bf) * 32768)

// stage A K-tile kt (256x64, 32KB) into buf bf: 4 x global_load_lds / thread
#define STG_A(bf, kt) { \
    const unsigned short* _g = xb + (size_t)(m0 + srow) * Dc + (kt) * BK + scol_sw; \
    _Pragma("unroll") for (int c = 0; c < 4; ++c) \
        stage16(_g + (size_t)c * 64 * Dc, LDSA(bf) + c * 8192 + tid * 16); }

    // swizzled ds_read byte offsets within a 128-byte row
    const int swz   = (l15 & 7) << 4;
    const int offk0 = ((l4 * 16) ^ swz);
    const int offk1 = ((64 + l4 * 16) ^ swz);

// A fragment reads for one m-half: 8 x ds_read_b128
#define RD_A(dst, bf, mh) { \
    _Pragma("unroll") for (int mf = 0; mf < 4; ++mf) { \
        dst[mf][0] = *(const bf16x8*)(LDSA(bf) + (wr * 128 + (mh) * 64 + mf * 16 + l15) * 128 + offk0); \
        dst[mf][1] = *(const bf16x8*)(LDSA(bf) + (wr * 128 + (mh) * 64 + mf * 16 + l15) * 128 + offk1); } }

    // B direct-gather base: lane reads row (h0+wc*64+nq*16+l15), k = l4*8 ...
    const unsigned short* gBlane =
        w1b + (size_t)(h0 + wc * 64 + l15) * Dc + l4 * 8;

// load all 8 B fragments of K-tile kt into registers (8 x global 16B)
#define LD_B(dst, kt) { \
    _Pragma("unroll") for (int nq = 0; nq < 4; ++nq) \
    _Pragma("unroll") for (int kk = 0; kk < 2; ++kk) \
        dst[nq][kk] = *(const bf16x8*)(gBlane + (size_t)nq * 16 * Dc + (kt) * BK + kk * 32); }

// one m-half x all 4 n-fragments x K=64 : 32 MFMA
#define MMH(av, bv, mh) { \
    __builtin_amdgcn_s_setprio(1); \
    _Pragma("unroll") for (int mf = 0; mf < 4; ++mf) \
    _Pragma("unroll") for (int nq = 0; nq < 4; ++nq) { \
        acc[(mh)*4+mf][nq] = __builtin_amdgcn_mfma_f32_16x16x32_bf16( \
            av[mf][0], bv[nq][0], acc[(mh)*4+mf][nq], 0, 0, 0); \
        acc[(mh)*4+mf][nq] = __builtin_amdgcn_mfma_f32_16x16x32_bf16( \
            av[mf][1], bv[nq][1], acc[(mh)*4+mf][nq], 0, 0, 0); } \
    __builtin_amdgcn_s_setprio(0); }

    bf16x8 a[4][2], pBe[4][2], pBo[4][2];
    f32x4  acc[8][4];
    #pragma unroll
    for (int m = 0; m < 8; ++m)
        #pragma unroll
        for (int n = 0; n < 4; ++n) acc[m][n] = (f32x4)(0.0f);

    // prologue: A tile0 -> buf0; B tile0 -> pBe
    STG_A(0, 0);
    LD_B(pBe, 0);
    __syncthreads();   // drains vmcnt(0)

    for (int t = 0; t < KTILES / 2; ++t) {
        const int ko = 2 * t + 1;
        // even tile 2t: compute from buf0 + pBe; prefetch tile ko
        STG_A(1, ko);
        LD_B(pBo, ko);
        RD_A(a, 0, 0);
        MMH(a, pBe, 0);
        RD_A(a, 0, 1);
        MMH(a, pBe, 1);
        __syncthreads();
        // odd tile ko: compute from buf1 + pBo; prefetch tile ko+1
        if (ko + 1 < KTILES) {
            STG_A(0, ko + 1);
            LD_B(pBe, ko + 1);
        }
        RD_A(a, 1, 0);
        MMH(a, pBo, 0);
        RD_A(a, 1, 1);
        MMH(a, pBo, 1);
        __syncthreads();
    }

    // fold: +b1, relu, *W2 -> per-row partials, then reduce over l15 columns
    float sp[8][4];
    #pragma unroll
    for (int m = 0; m < 8; ++m)
        #pragma unroll
        for (int j = 0; j < 4; ++j) sp[m][j] = 0.0f;
    #pragma unroll
    for (int n = 0; n < 4; ++n)
        #pragma unroll
        for (int m = 0; m < 8; ++m)
            #pragma unroll
            for (int j = 0; j < 4; ++j) {
                float v = acc[m][n][j] + b1v[n];
                v = v > 0.0f ? v : 0.0f;
                sp[m][j] += v * w2v[n];
            }

    #pragma unroll
    for (int m = 0; m < 8; ++m)
        #pragma unroll
        for (int j = 0; j < 4; ++j) {
            float v = sp[m][j];
            v += __shfl_xor(v, 1);
            v += __shfl_xor(v, 2);
            v += __shfl_xor(v, 4);
            v += __shfl_xor(v, 8);
            sp[m][j] = v;
        }

    if (l15 == 0) {
        const size_t base = (size_t)(ht * 4 + wc) * Mc;
        #pragma unroll
        for (int m = 0; m < 8; ++m)
            #pragma unroll
            for (int j = 0; j < 4; ++j) {
                const int row = m0 + wr * 128 + m * 16 + l4 * 4 + j;
                score_part[base + row] = sp[m][j];
            }
    }
}

// ---------------- Kernel D: finalize + write filter matrix ------------------
__global__ void __launch_bounds__(256) finalize(
    const float* __restrict__ score_part, const float* __restrict__ energy,
    const float* __restrict__ b2, float* __restrict__ out)
{
    const int row = blockIdx.x * 2 + (threadIdx.x >> 7);  // 0..Mc-1
    const int t   = threadIdx.x & 127;                    // 128 thr per row

    float s = b2[0];
    #pragma unroll
    for (int g = 0; g < NSLICE; ++g) s += score_part[(size_t)g * Mc + row];
    const float attn = (1.0f / (1.0f + expf(-s))) * energy[row];

    const int n = row & (Nc - 1);
    float4 z = make_float4(0.0f, 0.0f, 0.0f, 0.0f);
    if (t == (n >> 2)) ((float*)&z)[n & 3] = attn;
    ((float4*)(out + (size_t)row * Nc))[t] = z;
    if (t == 0) out[(size_t)Bc * Nc * Nc + row] = attn;
}

// ---------------- Host launcher ---------------------------------------------
extern "C" void kernel_launch(void* const* d_in, const int* in_sizes, int n_in,
                              void* d_out, int out_size, void* d_ws, size_t ws_size,
                              hipStream_t stream) {
    const float* x  = (const float*)d_in[0];
    const float* W1 = (const float*)d_in[1];
    const float* b1 = (const float*)d_in[2];
    const float* W2 = (const float*)d_in[3];
    const float* b2 = (const float*)d_in[4];
    float* out = (float*)d_out;

    const size_t xb_bytes = (size_t)Mc * Dc * 2;     // 64 MB
    const size_t w1_bytes = (size_t)Hc * Dc * 2;     // 4 MB
    const size_t e_bytes  = (size_t)Mc * 4;          // 128 KB
    const size_t s_bytes  = (size_t)NSLICE * Mc * 4; // 4 MB

    char* ws = (char*)d_ws;
    unsigned short* xb;
    if (ws_size >= xb_bytes + w1_bytes + e_bytes + s_bytes + 256) {
        xb = (unsigned short*)ws; ws += xb_bytes;
    } else {
        // use the filter region of d_out (67 MB >= 64 MB) as bf16-x scratch;
        // finalize() fully overwrites it afterwards.
        xb = (unsigned short*)d_out;
    }
    unsigned short* w1b = (unsigned short*)ws; ws += w1_bytes;
    float* energy = (float*)ws; ws += e_bytes;
    float* score  = (float*)ws; ws += s_bytes;

    const int w1_blocks = (Hc * Dc / 4) / 256;       // 2048
    cast_fused<<<Mc + w1_blocks, 256, 0, stream>>>(x, W1, xb, w1b, energy);
    fused_gemm_score<<<MTILES * HTILES, 512, 65536, stream>>>(xb, w1b, b1, W2, score);
    finalize<<<Mc / 2, 256, 0, stream>>>(score, energy, b2, out);
}

// Round 11
// 165.215 us; speedup vs baseline: 1.5557x; 1.5557x over previous
//
#include <hip/hip_runtime.h>
#include <hip/hip_bf16.h>

// Problem constants (B,N,D,H from reference)
#define Bc 64
#define Nc 512
#define Dc 1024
#define Hc 2048
#define Mc (Bc * Nc)          // 32768 rows

// GEMM tiling: 256x256 tile, BK=64, 8 waves (2M x 4N), double-buffered LDS
#define BM 256
#define BH 256
#define BK 64
#define KTILES (Dc / BK)      // 16
#define MTILES (Mc / BM)      // 128
#define HTILES (Hc / BH)      // 8
#define NSLICE (HTILES * 4)   // 32 score slices (ht x wave-column)

typedef __attribute__((ext_vector_type(8))) short bf16x8;
typedef __attribute__((ext_vector_type(4))) float f32x4;

__device__ __forceinline__ unsigned short f2bf(float f) {
    unsigned u = __float_as_uint(f);
    u += 0x7FFFu + ((u >> 16) & 1u);   // RNE
    return (unsigned short)(u >> 16);
}

__device__ __forceinline__ void stage16(const void* g, void* l) {
    __builtin_amdgcn_global_load_lds(
        (const __attribute__((address_space(1))) unsigned int*)g,
        (__attribute__((address_space(3))) unsigned int*)l,
        16, 0, 0);
}

// ------- Kernel A: fused {cast x + energy (1 wave/row)} | {cast W1} ---------
__global__ void __launch_bounds__(256) cast_fused(
    const float* __restrict__ x, const float* __restrict__ w1,
    unsigned short* __restrict__ xb, unsigned short* __restrict__ w1b,
    float* __restrict__ energy)
{
    const int tid = threadIdx.x;
    if (blockIdx.x < Mc / 4) {
        // 4 rows per block, one wave per row: pure shfl reduce, no barriers
        const int row  = blockIdx.x * 4 + (tid >> 6);
        const int lane = tid & 63;
        const float4* src = (const float4*)(x + (size_t)row * Dc);
        ushort4* dst = (ushort4*)(xb + (size_t)row * Dc);
        float s = 0.0f;
        #pragma unroll
        for (int j = 0; j < 4; ++j) {
            const float4 v = src[lane + j * 64];
            ushort4 o;
            o.x = f2bf(v.x); o.y = f2bf(v.y); o.z = f2bf(v.z); o.w = f2bf(v.w);
            dst[lane + j * 64] = o;
            s += v.x * v.x + v.y * v.y + v.z * v.z + v.w * v.w;
        }
        #pragma unroll
        for (int m = 1; m < 64; m <<= 1) s += __shfl_xor(s, m);
        if (lane == 0) energy[row] = 1.0f / (1.0f + expf(-s));
    } else {
        const size_t i = (size_t)(blockIdx.x - Mc / 4) * 256 + tid; // x4 elems
        const float4 v = ((const float4*)w1)[i];
        ushort4 o;
        o.x = f2bf(v.x); o.y = f2bf(v.y); o.z = f2bf(v.z); o.w = f2bf(v.w);
        ((ushort4*)w1b)[i] = o;
    }
}

// ---------------- Kernel C: fused bf16 GEMM + relu + W2-reduce --------------
// 256x256 tile per block, 8 waves, double-buffered LDS, prefetch-1 staging
// (R5 core, unchanged). Additionally zero-fills a disjoint 64KB slice of the
// output filter matrix via idle store-pipe slots (zf != nullptr path).
// score_part[(ht*4 + wc)*Mc + row] = sum over slice's 64 h of
//     relu(x.W1[h] + b1[h]) * W2[h]
__global__ void __launch_bounds__(512, 2) fused_gemm_score(
    const unsigned short* __restrict__ xb,    // [Mc][Dc] bf16 bits
    const unsigned short* __restrict__ w1b,   // [Hc][Dc] bf16 bits
    const float* __restrict__ b1,             // [Hc]
    const float* __restrict__ w2,             // [Hc]
    float* __restrict__ score_part,           // [NSLICE][Mc]
    float* __restrict__ zf)                   // filter base to zero, or null
{
    // dynamic LDS: [2 buf][2 mat][256*64] bf16 = 128 KB
    extern __shared__ __attribute__((aligned(16))) unsigned short lds[];

    const int tid  = threadIdx.x;
    const int lane = tid & 63;
    const int wid  = tid >> 6;                // 0..7
    const int wr   = wid >> 2;                // 0..1  (m half: 128 rows)
    const int wc   = wid & 3;                 // 0..3  (h quarter: 64 cols)
    const int l15  = lane & 15;
    const int l4   = lane >> 4;               // 0..3

    // bijective XCD swizzle (1024 % 8 == 0): ht fastest within an XCD so the
    // 8 blocks sharing one x-tile run adjacently; W1 (4MB) stays L2-resident.
    const int b  = blockIdx.x;
    const int wg = (b & 7) * (MTILES * HTILES / 8) + (b >> 3);
    const int mt = wg >> 3;                   // 0..127
    const int ht = wg & 7;                    // 0..7
    const int m0 = mt * BM;
    const int h0 = ht * BH;

    // epilogue coefficients prefetch
    float b1v[4], w2v[4];
    #pragma unroll
    for (int n = 0; n < 4; ++n) {
        const int h = h0 + wc * 64 + n * 16 + l15;
        b1v[n] = b1[h];
        w2v[n] = w2[h];
    }

    // staging geometry (rule #21: linear LDS dest + pre-swizzled src col)
    const int srow    = tid >> 3;             // 0..63
    const int scol_sw = ((((tid & 7) * 16) ^ ((srow & 7) << 4)) >> 1); // elems

    unsigned short* A0p = lds;                // [buf*32768 + mat*16384] elems
    #define LDSBUF(buf, mat) (A0p + (buf) * 32768 + (mat) * 16384)

    // swizzled ds_read byte offsets within a 128-byte row
    const int swz   = (l15 & 7) << 4;
    const int offk0 = ((l4 * 16) ^ swz);
    const int offk1 = ((64 + l4 * 16) ^ swz);
    const int arow  = (wr * 128 + l15) * 128; // byte row base within A
    const int brow  = (wc * 64 + l15) * 128;  // byte row base within B

// fragment reads (8 b128 for an A m-half, 4 b128 for a B n-half)
#define RD_A(dst, bf, mh) { \
    _Pragma("unroll") for (int mf = 0; mf < 4; ++mf) { \
        dst[mf][0] = *(const bf16x8*)((char*)LDSBUF(bf, 0) + arow + ((mh)*64 + mf*16) * 128 + offk0); \
        dst[mf][1] = *(const bf16x8*)((char*)LDSBUF(bf, 0) + arow + ((mh)*64 + mf*16) * 128 + offk1); } }
#define RD_B(dst, bf, nh) { \
    _Pragma("unroll") for (int nf = 0; nf < 2; ++nf) { \
        dst[nf][0] = *(const bf16x8*)((char*)LDSBUF(bf, 1) + brow + ((nh)*32 + nf*16) * 128 + offk0); \
        dst[nf][1] = *(const bf16x8*)((char*)LDSBUF(bf, 1) + brow + ((nh)*32 + nf*16) * 128 + offk1); } }

// one C-quadrant (m-half x n-half) x K=64 : 16 MFMA
#define MMQ(av, bv, mh, nh) { \
    __builtin_amdgcn_s_setprio(1); \
    _Pragma("unroll") for (int mf = 0; mf < 4; ++mf) \
    _Pragma("unroll") for (int nf = 0; nf < 2; ++nf) { \
        acc[(mh)*4+mf][(nh)*2+nf] = __builtin_amdgcn_mfma_f32_16x16x32_bf16( \
            av[mf][0], bv[nf][0], acc[(mh)*4+mf][(nh)*2+nf], 0, 0, 0); \
        acc[(mh)*4+mf][(nh)*2+nf] = __builtin_amdgcn_mfma_f32_16x16x32_bf16( \
            av[mf][1], bv[nf][1], acc[(mh)*4+mf][(nh)*2+nf], 0, 0, 0); } \
    __builtin_amdgcn_s_setprio(0); }

    f32x4 acc[8][4];
    #pragma unroll
    for (int m = 0; m < 8; ++m)
        #pragma unroll
        for (int n = 0; n < 4; ++n) acc[m][n] = (f32x4)(0.0f);

    // zero-fill slice base: block b owns out[b*16384 .. b*16384+16383]
    f32x4* zbase = zf ? (f32x4*)(zf + (size_t)b * 16384 + tid * 4) : nullptr;
    const f32x4 zero4 = (f32x4)(0.0f);

    // prologue: stage K-tile 0 into buf 0
    #pragma unroll
    for (int c = 0; c < 4; ++c) {
        stage16(xb  + (size_t)(m0 + c * 64 + srow) * Dc + scol_sw,
                ((char*)LDSBUF(0, 0)) + c * 8192 + tid * 16);
        stage16(w1b + (size_t)(h0 + c * 64 + srow) * Dc + scol_sw,
                ((char*)LDSBUF(0, 1)) + c * 8192 + tid * 16);
    }
    __syncthreads();   // compiler drains vmcnt(0) here

    int cur = 0;
    for (int kt = 0; kt < KTILES; ++kt) {
        // issue next-tile staging first: in flight across this tile's compute
        if (kt + 1 < KTILES) {
            const int k0 = (kt + 1) * BK;
            const int nb = cur ^ 1;
            #pragma unroll
            for (int c = 0; c < 4; ++c) {
                stage16(xb  + (size_t)(m0 + c * 64 + srow) * Dc + k0 + scol_sw,
                        ((char*)LDSBUF(nb, 0)) + c * 8192 + tid * 16);
                stage16(w1b + (size_t)(h0 + c * 64 + srow) * Dc + k0 + scol_sw,
                        ((char*)LDSBUF(nb, 1)) + c * 8192 + tid * 16);
            }
        }

        // idle-store-pipe zero-fill: one nontemporal 16B store on kt=0..7
        if (zbase && kt < 8)
            __builtin_nontemporal_store(zero4, zbase + (size_t)kt * 512);

        bf16x8 a0[4][2], a1[4][2], b0[2][2], b1f[2][2];

        // software pipeline: reads for quadrant q+1 issued BEFORE MFMA(q)
        RD_A(a0, cur, 0); RD_B(b0, cur, 0);   // q0 operands (8-read burst)
        RD_B(b1f, cur, 1);                    // q1 operand, under MM(q0)
        MMQ(a0, b0, 0, 0);
        RD_A(a1, cur, 1);                     // q2 operand, under MM(q1)
        MMQ(a0, b1f, 0, 1);
        MMQ(a1, b1f, 1, 1);
        MMQ(a1, b0, 1, 0);

        __syncthreads();   // next buffer staged; all reads of cur done
        cur ^= 1;
    }

    // fold: +b1, relu, *W2 -> per-row partials, then reduce over l15 columns
    float sp[8][4];
    #pragma unroll
    for (int m = 0; m < 8; ++m)
        #pragma unroll
        for (int j = 0; j < 4; ++j) sp[m][j] = 0.0f;
    #pragma unroll
    for (int n = 0; n < 4; ++n)
        #pragma unroll
        for (int m = 0; m < 8; ++m)
            #pragma unroll
            for (int j = 0; j < 4; ++j) {
                float v = acc[m][n][j] + b1v[n];
                v = v > 0.0f ? v : 0.0f;
                sp[m][j] += v * w2v[n];
            }

    #pragma unroll
    for (int m = 0; m < 8; ++m)
        #pragma unroll
        for (int j = 0; j < 4; ++j) {
            float v = sp[m][j];
            v += __shfl_xor(v, 1);
            v += __shfl_xor(v, 2);
            v += __shfl_xor(v, 4);
            v += __shfl_xor(v, 8);
            sp[m][j] = v;
        }

    if (l15 == 0) {
        const size_t base = (size_t)(ht * 4 + wc) * Mc;
        #pragma unroll
        for (int m = 0; m < 8; ++m)
            #pragma unroll
            for (int j = 0; j < 4; ++j) {
                const int row = m0 + wr * 128 + m * 16 + l4 * 4 + j;
                score_part[base + row] = sp[m][j];
            }
    }
}

// -------- Kernel D (fast path): diagonal + attn scatter only ----------------
__global__ void __launch_bounds__(256) finalize_scatter(
    const float* __restrict__ score_part, const float* __restrict__ energy,
    const float* __restrict__ b2, float* __restrict__ out)
{
    const int row = blockIdx.x * 256 + threadIdx.x;       // 0..Mc-1
    float s = b2[0];
    #pragma unroll
    for (int g = 0; g < NSLICE; ++g) s += score_part[(size_t)g * Mc + row];
    const float attn = (1.0f / (1.0f + expf(-s))) * energy[row];
    const int bb = row >> 9;              // batch
    const int n  = row & (Nc - 1);
    out[(size_t)bb * Nc * Nc + (size_t)n * (Nc + 1)] = attn;   // diagonal
    out[(size_t)Bc * Nc * Nc + row] = attn;                    // attn vector
}

// -------- Kernel D (fallback): full filter write (zeros + diag) -------------
__global__ void __launch_bounds__(256) finalize_full(
    const float* __restrict__ score_part, const float* __restrict__ energy,
    const float* __restrict__ b2, float* __restrict__ out)
{
    const int row = blockIdx.x * 2 + (threadIdx.x >> 7);  // 0..Mc-1
    const int t   = threadIdx.x & 127;                    // 128 thr per row

    float s = b2[0];
    #pragma unroll
    for (int g = 0; g < NSLICE; ++g) s += score_part[(size_t)g * Mc + row];
    const float attn = (1.0f / (1.0f + expf(-s))) * energy[row];

    const int n = row & (Nc - 1);
    float4 z = make_float4(0.0f, 0.0f, 0.0f, 0.0f);
    if (t == (n >> 2)) ((float*)&z)[n & 3] = attn;
    ((float4*)(out + (size_t)row * Nc))[t] = z;
    if (t == 0) out[(size_t)Bc * Nc * Nc + row] = attn;
}

// ---------------- Host launcher ---------------------------------------------
extern "C" void kernel_launch(void* const* d_in, const int* in_sizes, int n_in,
                              void* d_out, int out_size, void* d_ws, size_t ws_size,
                              hipStream_t stream) {
    const float* x  = (const float*)d_in[0];
    const float* W1 = (const float*)d_in[1];
    const float* b1 = (const float*)d_in[2];
    const float* W2 = (const float*)d_in[3];
    const float* b2 = (const float*)d_in[4];
    float* out = (float*)d_out;

    const size_t xb_bytes = (size_t)Mc * Dc * 2;     // 64 MB
    const size_t w1_bytes = (size_t)Hc * Dc * 2;     // 4 MB
    const size_t e_bytes  = (size_t)Mc * 4;          // 128 KB
    const size_t s_bytes  = (size_t)NSLICE * Mc * 4; // 4 MB

    char* ws = (char*)d_ws;
    unsigned short* xb;
    bool xb_in_out = false;
    if (ws_size >= xb_bytes + w1_bytes + e_bytes + s_bytes + 256) {
        xb = (unsigned short*)ws; ws += xb_bytes;
    } else {
        // use the filter region of d_out (67 MB >= 64 MB) as bf16-x scratch;
        // finalize_full fully overwrites it afterwards.
        xb = (unsigned short*)d_out;
        xb_in_out = true;
    }
    unsigned short* w1b = (unsigned short*)ws; ws += w1_bytes;
    float* energy = (float*)ws; ws += e_bytes;
    float* score  = (float*)ws; ws += s_bytes;

    const int w1_blocks = (Hc * Dc / 4) / 256;       // 2048
    cast_fused<<<Mc / 4 + w1_blocks, 256, 0, stream>>>(x, W1, xb, w1b, energy);
    fused_gemm_score<<<MTILES * HTILES, 512, 131072, stream>>>(
        xb, w1b, b1, W2, score, xb_in_out ? nullptr : out);
    if (xb_in_out)
        finalize_full<<<Mc / 2, 256, 0, stream>>>(score, energy, b2, out);
    else
        finalize_scatter<<<Mc / 256, 256, 0, stream>>>(score, energy, b2, out);
}

// Round 12
// 153.219 us; speedup vs baseline: 1.6775x; 1.0783x over previous
//
#include <hip/hip_runtime.h>
#include <hip/hip_bf16.h>

// Problem constants (B,N,D,H from reference)
#define Bc 64
#define Nc 512
#define Dc 1024
#define Hc 2048
#define Mc (Bc * Nc)          // 32768 rows

// GEMM tiling: 256x256 tile, BK=64, 8 waves (2M x 4N), double-buffered LDS
#define BM 256
#define BH 256
#define BK 64
#define KTILES (Dc / BK)      // 16
#define MTILES (Mc / BM)      // 128
#define HTILES (Hc / BH)      // 8
#define NSLICE (HTILES * 4)   // 32 score slices (ht x wave-column)

typedef __attribute__((ext_vector_type(8))) short bf16x8;
typedef __attribute__((ext_vector_type(4))) float f32x4;

__device__ __forceinline__ unsigned short f2bf(float f) {
    unsigned u = __float_as_uint(f);
    u += 0x7FFFu + ((u >> 16) & 1u);   // RNE
    return (unsigned short)(u >> 16);
}

__device__ __forceinline__ void stage16(const void* g, void* l) {
    __builtin_amdgcn_global_load_lds(
        (const __attribute__((address_space(1))) unsigned int*)g,
        (__attribute__((address_space(3))) unsigned int*)l,
        16, 0, 0);
}

// ------- Kernel A: fused {cast x + energy (1 wave/row)} | {cast W1} ---------
__global__ void __launch_bounds__(256) cast_fused(
    const float* __restrict__ x, const float* __restrict__ w1,
    unsigned short* __restrict__ xb, unsigned short* __restrict__ w1b,
    float* __restrict__ energy)
{
    const int tid = threadIdx.x;
    if (blockIdx.x < Mc / 4) {
        // 4 rows per block, one wave per row: pure shfl reduce, no barriers
        const int row  = blockIdx.x * 4 + (tid >> 6);
        const int lane = tid & 63;
        const float4* src = (const float4*)(x + (size_t)row * Dc);
        ushort4* dst = (ushort4*)(xb + (size_t)row * Dc);
        float s = 0.0f;
        #pragma unroll
        for (int j = 0; j < 4; ++j) {
            const float4 v = src[lane + j * 64];
            ushort4 o;
            o.x = f2bf(v.x); o.y = f2bf(v.y); o.z = f2bf(v.z); o.w = f2bf(v.w);
            dst[lane + j * 64] = o;
            s += v.x * v.x + v.y * v.y + v.z * v.z + v.w * v.w;
        }
        #pragma unroll
        for (int m = 1; m < 64; m <<= 1) s += __shfl_xor(s, m);
        if (lane == 0) energy[row] = 1.0f / (1.0f + expf(-s));
    } else {
        const size_t i = (size_t)(blockIdx.x - Mc / 4) * 256 + tid; // x4 elems
        const float4 v = ((const float4*)w1)[i];
        ushort4 o;
        o.x = f2bf(v.x); o.y = f2bf(v.y); o.z = f2bf(v.z); o.w = f2bf(v.w);
        ((ushort4*)w1b)[i] = o;
    }
}

// ---------------- Kernel C: fused bf16 GEMM + relu + W2-reduce --------------
// 256x256 tile per block, 8 waves, double-buffered LDS, prefetch-1 staging
// (R5 core; setprio removed per m190: hurts lockstep 2-barrier GEMMs).
// Additionally zero-fills a disjoint 64KB slice of the output filter matrix
// via idle store-pipe slots on kt>=8 (settled pipeline; zf != nullptr path).
// score_part[(ht*4 + wc)*Mc + row] = sum over slice's 64 h of
//     relu(x.W1[h] + b1[h]) * W2[h]
__global__ void __launch_bounds__(512, 2) fused_gemm_score(
    const unsigned short* __restrict__ xb,    // [Mc][Dc] bf16 bits
    const unsigned short* __restrict__ w1b,   // [Hc][Dc] bf16 bits
    const float* __restrict__ b1,             // [Hc]
    const float* __restrict__ w2,             // [Hc]
    float* __restrict__ score_part,           // [NSLICE][Mc]
    float* __restrict__ zf)                   // filter base to zero, or null
{
    // dynamic LDS: [2 buf][2 mat][256*64] bf16 = 128 KB
    extern __shared__ __attribute__((aligned(16))) unsigned short lds[];

    const int tid  = threadIdx.x;
    const int lane = tid & 63;
    const int wid  = tid >> 6;                // 0..7
    const int wr   = wid >> 2;                // 0..1  (m half: 128 rows)
    const int wc   = wid & 3;                 // 0..3  (h quarter: 64 cols)
    const int l15  = lane & 15;
    const int l4   = lane >> 4;               // 0..3

    // bijective XCD swizzle (1024 % 8 == 0): ht fastest within an XCD so the
    // 8 blocks sharing one x-tile run adjacently; W1 (4MB) stays L2-resident.
    const int b  = blockIdx.x;
    const int wg = (b & 7) * (MTILES * HTILES / 8) + (b >> 3);
    const int mt = wg >> 3;                   // 0..127
    const int ht = wg & 7;                    // 0..7
    const int m0 = mt * BM;
    const int h0 = ht * BH;

    // epilogue coefficients prefetch
    float b1v[4], w2v[4];
    #pragma unroll
    for (int n = 0; n < 4; ++n) {
        const int h = h0 + wc * 64 + n * 16 + l15;
        b1v[n] = b1[h];
        w2v[n] = w2[h];
    }

    // staging geometry (rule #21: linear LDS dest + pre-swizzled src col)
    const int srow    = tid >> 3;             // 0..63
    const int scol_sw = ((((tid & 7) * 16) ^ ((srow & 7) << 4)) >> 1); // elems

    unsigned short* A0p = lds;                // [buf*32768 + mat*16384] elems
    #define LDSBUF(buf, mat) (A0p + (buf) * 32768 + (mat) * 16384)

    // swizzled ds_read byte offsets within a 128-byte row
    const int swz   = (l15 & 7) << 4;
    const int offk0 = ((l4 * 16) ^ swz);
    const int offk1 = ((64 + l4 * 16) ^ swz);
    const int arow  = (wr * 128 + l15) * 128; // byte row base within A
    const int brow  = (wc * 64 + l15) * 128;  // byte row base within B

// fragment reads (8 b128 for an A m-half, 4 b128 for a B n-half)
#define RD_A(dst, bf, mh) { \
    _Pragma("unroll") for (int mf = 0; mf < 4; ++mf) { \
        dst[mf][0] = *(const bf16x8*)((char*)LDSBUF(bf, 0) + arow + ((mh)*64 + mf*16) * 128 + offk0); \
        dst[mf][1] = *(const bf16x8*)((char*)LDSBUF(bf, 0) + arow + ((mh)*64 + mf*16) * 128 + offk1); } }
#define RD_B(dst, bf, nh) { \
    _Pragma("unroll") for (int nf = 0; nf < 2; ++nf) { \
        dst[nf][0] = *(const bf16x8*)((char*)LDSBUF(bf, 1) + brow + ((nh)*32 + nf*16) * 128 + offk0); \
        dst[nf][1] = *(const bf16x8*)((char*)LDSBUF(bf, 1) + brow + ((nh)*32 + nf*16) * 128 + offk1); } }

// one C-quadrant (m-half x n-half) x K=64 : 16 MFMA (no setprio: m190)
#define MMQ(av, bv, mh, nh) { \
    _Pragma("unroll") for (int mf = 0; mf < 4; ++mf) \
    _Pragma("unroll") for (int nf = 0; nf < 2; ++nf) { \
        acc[(mh)*4+mf][(nh)*2+nf] = __builtin_amdgcn_mfma_f32_16x16x32_bf16( \
            av[mf][0], bv[nf][0], acc[(mh)*4+mf][(nh)*2+nf], 0, 0, 0); \
        acc[(mh)*4+mf][(nh)*2+nf] = __builtin_amdgcn_mfma_f32_16x16x32_bf16( \
            av[mf][1], bv[nf][1], acc[(mh)*4+mf][(nh)*2+nf], 0, 0, 0); } }

    f32x4 acc[8][4];
    #pragma unroll
    for (int m = 0; m < 8; ++m)
        #pragma unroll
        for (int n = 0; n < 4; ++n) acc[m][n] = (f32x4)(0.0f);

    // zero-fill slice base: block b owns out[b*16384 .. b*16384+16383]
    f32x4* zbase = zf ? (f32x4*)(zf + (size_t)b * 16384 + tid * 4) : nullptr;
    const f32x4 zero4 = (f32x4)(0.0f);

    // prologue: stage K-tile 0 into buf 0
    #pragma unroll
    for (int c = 0; c < 4; ++c) {
        stage16(xb  + (size_t)(m0 + c * 64 + srow) * Dc + scol_sw,
                ((char*)LDSBUF(0, 0)) + c * 8192 + tid * 16);
        stage16(w1b + (size_t)(h0 + c * 64 + srow) * Dc + scol_sw,
                ((char*)LDSBUF(0, 1)) + c * 8192 + tid * 16);
    }
    __syncthreads();   // compiler drains vmcnt(0) here

    int cur = 0;
    for (int kt = 0; kt < KTILES; ++kt) {
        // issue next-tile staging first: in flight across this tile's compute
        if (kt + 1 < KTILES) {
            const int k0 = (kt + 1) * BK;
            const int nb = cur ^ 1;
            #pragma unroll
            for (int c = 0; c < 4; ++c) {
                stage16(xb  + (size_t)(m0 + c * 64 + srow) * Dc + k0 + scol_sw,
                        ((char*)LDSBUF(nb, 0)) + c * 8192 + tid * 16);
                stage16(w1b + (size_t)(h0 + c * 64 + srow) * Dc + k0 + scol_sw,
                        ((char*)LDSBUF(nb, 1)) + c * 8192 + tid * 16);
            }
        }

        // idle-store-pipe zero-fill: one nontemporal 16B store on kt=8..15
        // (after the pipeline has settled; prologue region is the most stalled)
        if (zbase && kt >= 8)
            __builtin_nontemporal_store(zero4, zbase + (size_t)(kt - 8) * 512);

        bf16x8 a0[4][2], a1[4][2], b0[2][2], b1f[2][2];

        // software pipeline: reads for quadrant q+1 issued BEFORE MFMA(q)
        RD_A(a0, cur, 0); RD_B(b0, cur, 0);   // q0 operands (8-read burst)
        RD_B(b1f, cur, 1);                    // q1 operand, under MM(q0)
        MMQ(a0, b0, 0, 0);
        RD_A(a1, cur, 1);                     // q2 operand, under MM(q1)
        MMQ(a0, b1f, 0, 1);
        MMQ(a1, b1f, 1, 1);
        MMQ(a1, b0, 1, 0);

        __syncthreads();   // next buffer staged; all reads of cur done
        cur ^= 1;
    }

    // fold: +b1, relu, *W2 -> per-row partials, then reduce over l15 columns
    float sp[8][4];
    #pragma unroll
    for (int m = 0; m < 8; ++m)
        #pragma unroll
        for (int j = 0; j < 4; ++j) sp[m][j] = 0.0f;
    #pragma unroll
    for (int n = 0; n < 4; ++n)
        #pragma unroll
        for (int m = 0; m < 8; ++m)
            #pragma unroll
            for (int j = 0; j < 4; ++j) {
                float v = acc[m][n][j] + b1v[n];
                v = v > 0.0f ? v : 0.0f;
                sp[m][j] += v * w2v[n];
            }

    #pragma unroll
    for (int m = 0; m < 8; ++m)
        #pragma unroll
        for (int j = 0; j < 4; ++j) {
            float v = sp[m][j];
            v += __shfl_xor(v, 1);
            v += __shfl_xor(v, 2);
            v += __shfl_xor(v, 4);
            v += __shfl_xor(v, 8);
            sp[m][j] = v;
        }

    if (l15 == 0) {
        const size_t base = (size_t)(ht * 4 + wc) * Mc;
        #pragma unroll
        for (int m = 0; m < 8; ++m)
            #pragma unroll
            for (int j = 0; j < 4; ++j) {
                const int row = m0 + wr * 128 + m * 16 + l4 * 4 + j;
                score_part[base + row] = sp[m][j];
            }
    }
}

// -------- Kernel D (fast path): diagonal + attn scatter only ----------------
__global__ void __launch_bounds__(256) finalize_scatter(
    const float* __restrict__ score_part, const float* __restrict__ energy,
    const float* __restrict__ b2, float* __restrict__ out)
{
    const int row = blockIdx.x * 256 + threadIdx.x;       // 0..Mc-1
    float s = b2[0];
    #pragma unroll
    for (int g = 0; g < NSLICE; ++g) s += score_part[(size_t)g * Mc + row];
    const float attn = (1.0f / (1.0f + expf(-s))) * energy[row];
    const int bb = row >> 9;              // batch
    const int n  = row & (Nc - 1);
    out[(size_t)bb * Nc * Nc + (size_t)n * (Nc + 1)] = attn;   // diagonal
    out[(size_t)Bc * Nc * Nc + row] = attn;                    // attn vector
}

// -------- Kernel D (fallback): full filter write (zeros + diag) -------------
__global__ void __launch_bounds__(256) finalize_full(
    const float* __restrict__ score_part, const float* __restrict__ energy,
    const float* __restrict__ b2, float* __restrict__ out)
{
    const int row = blockIdx.x * 2 + (threadIdx.x >> 7);  // 0..Mc-1
    const int t   = threadIdx.x & 127;                    // 128 thr per row

    float s = b2[0];
    #pragma unroll
    for (int g = 0; g < NSLICE; ++g) s += score_part[(size_t)g * Mc + row];
    const float attn = (1.0f / (1.0f + expf(-s))) * energy[row];

    const int n = row & (Nc - 1);
    float4 z = make_float4(0.0f, 0.0f, 0.0f, 0.0f);
    if (t == (n >> 2)) ((float*)&z)[n & 3] = attn;
    ((float4*)(out + (size_t)row * Nc))[t] = z;
    if (t == 0) out[(size_t)Bc * Nc * Nc + row] = attn;
}

// ---------------- Host launcher ---------------------------------------------
extern "C" void kernel_launch(void* const* d_in, const int* in_sizes, int n_in,
                              void* d_out, int out_size, void* d_ws, size_t ws_size,
                              hipStream_t stream) {
    const float* x  = (const float*)d_in[0];
    const float* W1 = (const float*)d_in[1];
    const float* b1 = (const float*)d_in[2];
    const float* W2 = (const float*)d_in[3];
    const float* b2 = (const float*)d_in[4];
    float* out = (float*)d_out;

    const size_t xb_bytes = (size_t)Mc * Dc * 2;     // 64 MB
    const size_t w1_bytes = (size_t)Hc * Dc * 2;     // 4 MB
    const size_t e_bytes  = (size_t)Mc * 4;          // 128 KB
    const size_t s_bytes  = (size_t)NSLICE * Mc * 4; // 4 MB

    char* ws = (char*)d_ws;
    unsigned short* xb;
    bool xb_in_out = false;
    if (ws_size >= xb_bytes + w1_bytes + e_bytes + s_bytes + 256) {
        xb = (unsigned short*)ws; ws += xb_bytes;
    } else {
        // use the filter region of d_out (67 MB >= 64 MB) as bf16-x scratch;
        // finalize_full fully overwrites it afterwards.
        xb = (unsigned short*)d_out;
        xb_in_out = true;
    }
    unsigned short* w1b = (unsigned short*)ws; ws += w1_bytes;
    float* energy = (float*)ws; ws += e_bytes;
    float* score  = (float*)ws; ws += s_bytes;

    const int w1_blocks = (Hc * Dc / 4) / 256;       // 2048
    cast_fused<<<Mc / 4 + w1_blocks, 256, 0, stream>>>(x, W1, xb, w1b, energy);
    fused_gemm_score<<<MTILES * HTILES, 512, 131072, stream>>>(
        xb, w1b, b1, W2, score, xb_in_out ? nullptr : out);
    if (xb_in_out)
        finalize_full<<<Mc / 2, 256, 0, stream>>>(score, energy, b2, out);
    else
        finalize_scatter<<<Mc / 256, 256, 0, stream>>>(score, energy, b2, out);
}

// Round 13
// 152.235 us; speedup vs baseline: 1.6884x; 1.0065x over previous
//
#include <hip/hip_runtime.h>
#include <hip/hip_bf16.h>

// Problem constants (B,N,D,H from reference)
#define Bc 64
#define Nc 512
#define Dc 1024
#define Hc 2048
#define Mc (Bc * Nc)          // 32768 rows

// GEMM tiling: 256x256 tile, BK=64, 8 waves (2M x 4N), double-buffered LDS
#define BM 256
#define BH 256
#define BK 64
#define KTILES (Dc / BK)      // 16
#define MTILES (Mc / BM)      // 128
#define HTILES (Hc / BH)      // 8
#define NSLICE (HTILES * 4)   // 32 score slices (ht x wave-column)

typedef __attribute__((ext_vector_type(8))) short bf16x8;
typedef __attribute__((ext_vector_type(4))) float f32x4;

__device__ __forceinline__ unsigned short f2bf(float f) {
    unsigned u = __float_as_uint(f);
    u += 0x7FFFu + ((u >> 16) & 1u);   // RNE
    return (unsigned short)(u >> 16);
}

__device__ __forceinline__ void stage16(const void* g, void* l) {
    __builtin_amdgcn_global_load_lds(
        (const __attribute__((address_space(1))) unsigned int*)g,
        (__attribute__((address_space(3))) unsigned int*)l,
        16, 0, 0);
}

// ------- Kernel A: fused {cast x + energy (2 rows/wave)} | {cast W1} --------
__global__ void __launch_bounds__(256) cast_fused(
    const float* __restrict__ x, const float* __restrict__ w1,
    unsigned short* __restrict__ xb, unsigned short* __restrict__ w1b,
    float* __restrict__ energy)
{
    const int tid = threadIdx.x;
    if (blockIdx.x < Mc / 8) {
        // 8 rows per block, two rows per wave: 8 independent float4 loads in
        // flight per lane (ILP) before the shfl-reduce tail; no barriers.
        const int row0 = blockIdx.x * 8 + (tid >> 6) * 2;
        const int lane = tid & 63;
        const float4* s0 = (const float4*)(x + (size_t)row0 * Dc);
        const float4* s1 = (const float4*)(x + (size_t)(row0 + 1) * Dc);
        ushort4* d0 = (ushort4*)(xb + (size_t)row0 * Dc);
        ushort4* d1 = (ushort4*)(xb + (size_t)(row0 + 1) * Dc);
        float4 v0[4], v1[4];
        #pragma unroll
        for (int j = 0; j < 4; ++j) v0[j] = s0[lane + j * 64];
        #pragma unroll
        for (int j = 0; j < 4; ++j) v1[j] = s1[lane + j * 64];
        float a = 0.0f, bsum = 0.0f;
        #pragma unroll
        for (int j = 0; j < 4; ++j) {
            ushort4 o;
            o.x = f2bf(v0[j].x); o.y = f2bf(v0[j].y);
            o.z = f2bf(v0[j].z); o.w = f2bf(v0[j].w);
            d0[lane + j * 64] = o;
            a += v0[j].x * v0[j].x + v0[j].y * v0[j].y +
                 v0[j].z * v0[j].z + v0[j].w * v0[j].w;
        }
        #pragma unroll
        for (int j = 0; j < 4; ++j) {
            ushort4 o;
            o.x = f2bf(v1[j].x); o.y = f2bf(v1[j].y);
            o.z = f2bf(v1[j].z); o.w = f2bf(v1[j].w);
            d1[lane + j * 64] = o;
            bsum += v1[j].x * v1[j].x + v1[j].y * v1[j].y +
                    v1[j].z * v1[j].z + v1[j].w * v1[j].w;
        }
        #pragma unroll
        for (int m = 1; m < 64; m <<= 1) {
            a    += __shfl_xor(a, m);
            bsum += __shfl_xor(bsum, m);
        }
        if (lane == 0) {
            energy[row0]     = 1.0f / (1.0f + expf(-a));
            energy[row0 + 1] = 1.0f / (1.0f + expf(-bsum));
        }
    } else {
        const size_t i = (size_t)(blockIdx.x - Mc / 8) * 256 + tid; // x4 elems
        const float4 v = ((const float4*)w1)[i];
        ushort4 o;
        o.x = f2bf(v.x); o.y = f2bf(v.y); o.z = f2bf(v.z); o.w = f2bf(v.w);
        ((ushort4*)w1b)[i] = o;
    }
}

// ---------------- Kernel C: fused bf16 GEMM + relu + W2-reduce --------------
// 256x256 tile per block, 8 waves, double-buffered LDS, prefetch-1 staging
// (R12 core, unchanged: no setprio — it fences the scheduler on lockstep
// schedules; zero-fill on kt>=8 via idle store pipe).
// score_part[(ht*4 + wc)*Mc + row] = sum over slice's 64 h of
//     relu(x.W1[h] + b1[h]) * W2[h]
__global__ void __launch_bounds__(512, 2) fused_gemm_score(
    const unsigned short* __restrict__ xb,    // [Mc][Dc] bf16 bits
    const unsigned short* __restrict__ w1b,   // [Hc][Dc] bf16 bits
    const float* __restrict__ b1,             // [Hc]
    const float* __restrict__ w2,             // [Hc]
    float* __restrict__ score_part,           // [NSLICE][Mc]
    float* __restrict__ zf)                   // filter base to zero, or null
{
    // dynamic LDS: [2 buf][2 mat][256*64] bf16 = 128 KB
    extern __shared__ __attribute__((aligned(16))) unsigned short lds[];

    const int tid  = threadIdx.x;
    const int lane = tid & 63;
    const int wid  = tid >> 6;                // 0..7
    const int wr   = wid >> 2;                // 0..1  (m half: 128 rows)
    const int wc   = wid & 3;                 // 0..3  (h quarter: 64 cols)
    const int l15  = lane & 15;
    const int l4   = lane >> 4;               // 0..3

    // bijective XCD swizzle (1024 % 8 == 0): ht fastest within an XCD so the
    // 8 blocks sharing one x-tile run adjacently; W1 (4MB) stays L2-resident.
    const int b  = blockIdx.x;
    const int wg = (b & 7) * (MTILES * HTILES / 8) + (b >> 3);
    const int mt = wg >> 3;                   // 0..127
    const int ht = wg & 7;                    // 0..7
    const int m0 = mt * BM;
    const int h0 = ht * BH;

    // epilogue coefficients prefetch
    float b1v[4], w2v[4];
    #pragma unroll
    for (int n = 0; n < 4; ++n) {
        const int h = h0 + wc * 64 + n * 16 + l15;
        b1v[n] = b1[h];
        w2v[n] = w2[h];
    }

    // staging geometry (rule #21: linear LDS dest + pre-swizzled src col)
    const int srow    = tid >> 3;             // 0..63
    const int scol_sw = ((((tid & 7) * 16) ^ ((srow & 7) << 4)) >> 1); // elems

    unsigned short* A0p = lds;                // [buf*32768 + mat*16384] elems
    #define LDSBUF(buf, mat) (A0p + (buf) * 32768 + (mat) * 16384)

    // swizzled ds_read byte offsets within a 128-byte row
    const int swz   = (l15 & 7) << 4;
    const int offk0 = ((l4 * 16) ^ swz);
    const int offk1 = ((64 + l4 * 16) ^ swz);
    const int arow  = (wr * 128 + l15) * 128; // byte row base within A
    const int brow  = (wc * 64 + l15) * 128;  // byte row base within B

// fragment reads (8 b128 for an A m-half, 4 b128 for a B n-half)
#define RD_A(dst, bf, mh) { \
    _Pragma("unroll") for (int mf = 0; mf < 4; ++mf) { \
        dst[mf][0] = *(const bf16x8*)((char*)LDSBUF(bf, 0) + arow + ((mh)*64 + mf*16) * 128 + offk0); \
        dst[mf][1] = *(const bf16x8*)((char*)LDSBUF(bf, 0) + arow + ((mh)*64 + mf*16) * 128 + offk1); } }
#define RD_B(dst, bf, nh) { \
    _Pragma("unroll") for (int nf = 0; nf < 2; ++nf) { \
        dst[nf][0] = *(const bf16x8*)((char*)LDSBUF(bf, 1) + brow + ((nh)*32 + nf*16) * 128 + offk0); \
        dst[nf][1] = *(const bf16x8*)((char*)LDSBUF(bf, 1) + brow + ((nh)*32 + nf*16) * 128 + offk1); } }

// one C-quadrant (m-half x n-half) x K=64 : 16 MFMA (no setprio: m190 + R12)
#define MMQ(av, bv, mh, nh) { \
    _Pragma("unroll") for (int mf = 0; mf < 4; ++mf) \
    _Pragma("unroll") for (int nf = 0; nf < 2; ++nf) { \
        acc[(mh)*4+mf][(nh)*2+nf] = __builtin_amdgcn_mfma_f32_16x16x32_bf16( \
            av[mf][0], bv[nf][0], acc[(mh)*4+mf][(nh)*2+nf], 0, 0, 0); \
        acc[(mh)*4+mf][(nh)*2+nf] = __builtin_amdgcn_mfma_f32_16x16x32_bf16( \
            av[mf][1], bv[nf][1], acc[(mh)*4+mf][(nh)*2+nf], 0, 0, 0); } }

    f32x4 acc[8][4];
    #pragma unroll
    for (int m = 0; m < 8; ++m)
        #pragma unroll
        for (int n = 0; n < 4; ++n) acc[m][n] = (f32x4)(0.0f);

    // zero-fill slice base: block b owns out[b*16384 .. b*16384+16383]
    f32x4* zbase = zf ? (f32x4*)(zf + (size_t)b * 16384 + tid * 4) : nullptr;
    const f32x4 zero4 = (f32x4)(0.0f);

    // prologue: stage K-tile 0 into buf 0
    #pragma unroll
    for (int c = 0; c < 4; ++c) {
        stage16(xb  + (size_t)(m0 + c * 64 + srow) * Dc + scol_sw,
                ((char*)LDSBUF(0, 0)) + c * 8192 + tid * 16);
        stage16(w1b + (size_t)(h0 + c * 64 + srow) * Dc + scol_sw,
                ((char*)LDSBUF(0, 1)) + c * 8192 + tid * 16);
    }
    __syncthreads();   // compiler drains vmcnt(0) here

    int cur = 0;
    for (int kt = 0; kt < KTILES; ++kt) {
        // issue next-tile staging first: in flight across this tile's compute
        if (kt + 1 < KTILES) {
            const int k0 = (kt + 1) * BK;
            const int nb = cur ^ 1;
            #pragma unroll
            for (int c = 0; c < 4; ++c) {
                stage16(xb  + (size_t)(m0 + c * 64 + srow) * Dc + k0 + scol_sw,
                        ((char*)LDSBUF(nb, 0)) + c * 8192 + tid * 16);
                stage16(w1b + (size_t)(h0 + c * 64 + srow) * Dc + k0 + scol_sw,
                        ((char*)LDSBUF(nb, 1)) + c * 8192 + tid * 16);
            }
        }

        // idle-store-pipe zero-fill: one nontemporal 16B store on kt=8..15
        if (zbase && kt >= 8)
            __builtin_nontemporal_store(zero4, zbase + (size_t)(kt - 8) * 512);

        bf16x8 a0[4][2], a1[4][2], b0[2][2], b1f[2][2];

        // software pipeline: reads for quadrant q+1 issued BEFORE MFMA(q)
        RD_A(a0, cur, 0); RD_B(b0, cur, 0);   // q0 operands (8-read burst)
        RD_B(b1f, cur, 1);                    // q1 operand, under MM(q0)
        MMQ(a0, b0, 0, 0);
        RD_A(a1, cur, 1);                     // q2 operand, under MM(q1)
        MMQ(a0, b1f, 0, 1);
        MMQ(a1, b1f, 1, 1);
        MMQ(a1, b0, 1, 0);

        __syncthreads();   // next buffer staged; all reads of cur done
        cur ^= 1;
    }

    // fold: +b1, relu, *W2 -> per-row partials, then reduce over l15 columns
    float sp[8][4];
    #pragma unroll
    for (int m = 0; m < 8; ++m)
        #pragma unroll
        for (int j = 0; j < 4; ++j) sp[m][j] = 0.0f;
    #pragma unroll
    for (int n = 0; n < 4; ++n)
        #pragma unroll
        for (int m = 0; m < 8; ++m)
            #pragma unroll
            for (int j = 0; j < 4; ++j) {
                float v = acc[m][n][j] + b1v[n];
                v = v > 0.0f ? v : 0.0f;
                sp[m][j] += v * w2v[n];
            }

    #pragma unroll
    for (int m = 0; m < 8; ++m)
        #pragma unroll
        for (int j = 0; j < 4; ++j) {
            float v = sp[m][j];
            v += __shfl_xor(v, 1);
            v += __shfl_xor(v, 2);
            v += __shfl_xor(v, 4);
            v += __shfl_xor(v, 8);
            sp[m][j] = v;
        }

    if (l15 == 0) {
        const size_t base = (size_t)(ht * 4 + wc) * Mc;
        #pragma unroll
        for (int m = 0; m < 8; ++m)
            #pragma unroll
            for (int j = 0; j < 4; ++j) {
                const int row = m0 + wr * 128 + m * 16 + l4 * 4 + j;
                score_part[base + row] = sp[m][j];
            }
    }
}

// -------- Kernel D (fast path): diagonal + attn scatter only ----------------
__global__ void __launch_bounds__(256) finalize_scatter(
    const float* __restrict__ score_part, const float* __restrict__ energy,
    const float* __restrict__ b2, float* __restrict__ out)
{
    const int row = blockIdx.x * 256 + threadIdx.x;       // 0..Mc-1
    float s = b2[0];
    #pragma unroll
    for (int g = 0; g < NSLICE; ++g) s += score_part[(size_t)g * Mc + row];
    const float attn = (1.0f / (1.0f + expf(-s))) * energy[row];
    const int bb = row >> 9;              // batch
    const int n  = row & (Nc - 1);
    out[(size_t)bb * Nc * Nc + (size_t)n * (Nc + 1)] = attn;   // diagonal
    out[(size_t)Bc * Nc * Nc + row] = attn;                    // attn vector
}

// -------- Kernel D (fallback): full filter write (zeros + diag) -------------
__global__ void __launch_bounds__(256) finalize_full(
    const float* __restrict__ score_part, const float* __restrict__ energy,
    const float* __restrict__ b2, float* __restrict__ out)
{
    const int row = blockIdx.x * 2 + (threadIdx.x >> 7);  // 0..Mc-1
    const int t   = threadIdx.x & 127;                    // 128 thr per row

    float s = b2[0];
    #pragma unroll
    for (int g = 0; g < NSLICE; ++g) s += score_part[(size_t)g * Mc + row];
    const float attn = (1.0f / (1.0f + expf(-s))) * energy[row];

    const int n = row & (Nc - 1);
    float4 z = make_float4(0.0f, 0.0f, 0.0f, 0.0f);
    if (t == (n >> 2)) ((float*)&z)[n & 3] = attn;
    ((float4*)(out + (size_t)row * Nc))[t] = z;
    if (t == 0) out[(size_t)Bc * Nc * Nc + row] = attn;
}

// ---------------- Host launcher ---------------------------------------------
extern "C" void kernel_launch(void* const* d_in, const int* in_sizes, int n_in,
                              void* d_out, int out_size, void* d_ws, size_t ws_size,
                              hipStream_t stream) {
    const float* x  = (const float*)d_in[0];
    const float* W1 = (const float*)d_in[1];
    const float* b1 = (const float*)d_in[2];
    const float* W2 = (const float*)d_in[3];
    const float* b2 = (const float*)d_in[4];
    float* out = (float*)d_out;

    const size_t xb_bytes = (size_t)Mc * Dc * 2;     // 64 MB
    const size_t w1_bytes = (size_t)Hc * Dc * 2;     // 4 MB
    const size_t e_bytes  = (size_t)Mc * 4;          // 128 KB
    const size_t s_bytes  = (size_t)NSLICE * Mc * 4; // 4 MB

    char* ws = (char*)d_ws;
    unsigned short* xb;
    bool xb_in_out = false;
    if (ws_size >= xb_bytes + w1_bytes + e_bytes + s_bytes + 256) {
        xb = (unsigned short*)ws; ws += xb_bytes;
    } else {
        // use the filter region of d_out (67 MB >= 64 MB) as bf16-x scratch;
        // finalize_full fully overwrites it afterwards.
        xb = (unsigned short*)d_out;
        xb_in_out = true;
    }
    unsigned short* w1b = (unsigned short*)ws; ws += w1_bytes;
    float* energy = (float*)ws; ws += e_bytes;
    float* score  = (float*)ws; ws += s_bytes;

    const int w1_blocks = (Hc * Dc / 4) / 256;       // 2048
    cast_fused<<<Mc / 8 + w1_blocks, 256, 0, stream>>>(x, W1, xb, w1b, energy);
    fused_gemm_score<<<MTILES * HTILES, 512, 131072, stream>>>(
        xb, w1b, b1, W2, score, xb_in_out ? nullptr : out);
    if (xb_in_out)
        finalize_full<<<Mc / 2, 256, 0, stream>>>(score, energy, b2, out);
    else
        finalize_scatter<<<Mc / 256, 256, 0, stream>>>(score, energy, b2, out);
}